// Round 6
// baseline (175.339 us; speedup 1.0000x reference)
//
#include <hip/hip_runtime.h>

// AI4Burgers: Lu = 0.5*conv3x3(u,w1) - u_vel*conv3x3(u,w2) - u_vel*conv3x3(u,w3)
// replicate pad, B=16, H=W=1024, fp32.
//
// R5 post-mortem: u went through un-sinkable global_load_lds DMA, but uvel
// stayed a register-destined load -> compiler sank it into the consume loop,
// keeping ~4 serialized global latencies per block (R4==R5==63us). Fix: stage
// uvel through DMA too. Now the block has ONE memory wait (the barrier's
// vmcnt(0) drain of 10 DMAs, 40KB in flight/block, 4 blocks/CU resident) and
// the consume phase is pure LDS+VALU. Also: R5's 5.7M LDS bank-conflict
// cycles came from stride-16B scalar ds_read_b32 halo reads (8-way) -> get
// the halo from __shfl of the loaded float4 (DPP, no LDS traffic); only the
// 2 wave-edge lanes do a predicated LDS patch read.

#define HH 1024
#define WW 1024
#define RPB 4                 // output rows per block
#define TPB 256               // 4 waves; wave w owns cols [256w, 256w+256)
#define NROW (RPB + 2)        // u rows staged (halo factor 1.5)

typedef __attribute__((address_space(3))) void       lds_void;
typedef __attribute__((address_space(1))) const void gbl_void;

__device__ __forceinline__ float rfl(float x) {
    union { float f; int i; } c; c.f = x;
    c.i = __builtin_amdgcn_readfirstlane(c.i);   // wave-uniform -> SGPR
    return c.f;
}

__global__ __launch_bounds__(TPB) void burgers_stencil(
    const float* __restrict__ u,
    const float* __restrict__ uvel,
    const float* __restrict__ w1,
    const float* __restrict__ w2,
    const float* __restrict__ w3,
    float* __restrict__ out,
    int rowBlocks)
{
    __shared__ float utile[NROW * WW];           // 24 KiB
    __shared__ float vtile[RPB  * WW];           // 16 KiB  (40 KiB total -> 4 blk/CU)

    const int tid  = threadIdx.x;
    const int wave = tid >> 6;
    const int lane = tid & 63;
    const int b    = blockIdx.x / rowBlocks;
    const int y0   = (blockIdx.x % rowBlocks) * RPB;
    const int x0   = tid * 4;

    const size_t img = (size_t)b * HH * WW;
    const float* ub  = u + img;
    const float* vb  = uvel + img;
    const int    col = wave * 256 + lane * 4;    // DMA column (same as x0)

    // ---- async DMA bursts: no destination VGPRs => scheduler cannot sink.
#pragma unroll
    for (int i = 0; i < NROW; ++i) {
        int yr = y0 - 1 + i;
        yr = yr < 0 ? 0 : (yr > HH - 1 ? HH - 1 : yr);       // replicate pad rows
        __builtin_amdgcn_global_load_lds(
            (gbl_void*)(ub + (size_t)yr * WW + col),
            (lds_void*)&utile[i * WW + col], 16, 0, 0);
    }
#pragma unroll
    for (int r = 0; r < RPB; ++r) {
        __builtin_amdgcn_global_load_lds(
            (gbl_void*)(vb + (size_t)(y0 + r) * WW + col),
            (lds_void*)&vtile[r * WW + col], 16, 0, 0);
    }

    // ---- weights -> SGPRs (fold w2+w3: Lu = 0.5*c1 - vel*(c2+c3))
    float W1[9], W23[9];
#pragma unroll
    for (int i = 0; i < 9; ++i) {
        W1[i]  = rfl(w1[i]);
        W23[i] = rfl(w2[i] + w3[i]);
    }

    __syncthreads();   // single wait: vmcnt(0) drains all 10 DMAs, then barrier

    // ---- consume: pure LDS + VALU. Halo via shfl; wave-edge lanes patch from
    //      LDS (block spans the full row, so the neighbor is always in utile).
#pragma unroll
    for (int r = 0; r < RPB; ++r) {
        float p[3][6];
#pragma unroll
        for (int rr = 0; rr < 3; ++rr) {
            const float* row = &utile[(r + rr) * WW];
            const float4 m = *(const float4*)(row + x0);     // ds_read_b128
            float left  = __shfl_up(m.w, 1);                 // px x0-1 (DPP)
            float right = __shfl_down(m.x, 1);               // px x0+4
            if (lane == 0)  left  = (x0 == 0)       ? m.x : row[x0 - 1];
            if (lane == 63) right = (x0 + 4 == WW)  ? m.w : row[x0 + 4];
            p[rr][0] = left;
            p[rr][1] = m.x; p[rr][2] = m.y;
            p[rr][3] = m.z; p[rr][4] = m.w;
            p[rr][5] = right;
        }
        const float4 vv = *(const float4*)(&vtile[r * WW] + x0);  // ds_read_b128
        const float vel[4] = {vv.x, vv.y, vv.z, vv.w};

        float o[4];
#pragma unroll
        for (int j = 0; j < 4; ++j) {
            float c1 = 0.f, c23 = 0.f;
#pragma unroll
            for (int rr = 0; rr < 3; ++rr) {
#pragma unroll
                for (int k = 0; k < 3; ++k) {
                    const float a = p[rr][j + k];
                    c1  = fmaf(W1[rr*3 + k],  a, c1);
                    c23 = fmaf(W23[rr*3 + k], a, c23);
                }
            }
            o[j] = 0.5f * c1 - vel[j] * c23;
        }
        float4 ov; ov.x = o[0]; ov.y = o[1]; ov.z = o[2]; ov.w = o[3];
        *(float4*)(out + img + (size_t)(y0 + r) * WW + x0) = ov;   // fire-and-forget
    }
}

extern "C" void kernel_launch(void* const* d_in, const int* in_sizes, int n_in,
                              void* d_out, int out_size, void* d_ws, size_t ws_size,
                              hipStream_t stream) {
    const float* u    = (const float*)d_in[0];
    const float* uvel = (const float*)d_in[1];
    const float* w1   = (const float*)d_in[2];
    const float* w2   = (const float*)d_in[3];
    const float* w3   = (const float*)d_in[4];
    float* out        = (float*)d_out;

    const int B = in_sizes[0] / (HH * WW);      // 16
    const int rowBlocks = HH / RPB;             // 256
    dim3 grid(B * rowBlocks);                   // 4096 blocks
    dim3 block(TPB);                            // 256 threads, 4 waves
    burgers_stencil<<<grid, block, 0, stream>>>(u, uvel, w1, w2, w3, out, rowBlocks);
}

// Round 7
// 174.331 us; speedup vs baseline: 1.0058x; 1.0058x over previous
//
#include <hip/hip_runtime.h>

// AI4Burgers: Lu = 0.5*conv3x3(u,w1) - u_vel*conv3x3(u,w2) - u_vel*conv3x3(u,w3)
// replicate pad, B=16, H=W=1024, fp32.
//
// R2-R6 all plateau at ~62-72us / ~2.4 TB/s regardless of structure. R6's
// counters show ~10us block lifetime for ~1.5us of work: the barriered
// burst-then-vmcnt(0) design makes all resident blocks issue and drain in
// lockstep (device-wide convoys with dead time between cohorts). Root cause
// of R3/R4's mysterious VGPR=32: the AMDGPU scheduler targets default-max
// occupancy unless amdgpu-waves-per-eu says otherwise, so register bursts
// were always sunk back to 1-2 deep chains.
//
// R7: single-wave blocks (64 thr), NO LDS, NO barriers. Each wave bursts its
// whole 8-row x 4-col tile into registers (10 u float4 + 20 clamped halo
// scalars + 8 uvel float4, ~18KB in flight, all independent), authorized by
// amdgpu_waves_per_eu(1,2) (~256 VGPR budget -> nothing forces sinking).
// 8192 independent waves retire asynchronously: continuous memory issue, no
// cohorts. Clamped scalar halo loads = replicate padding for free, and they
// hit lines fetched by neighboring waves' vector loads (L2-warm).

#define HH 1024
#define WW 1024
#define RPB 8                 // rows per wave
#define CPW 256               // columns per wave (64 lanes x 4 px)
#define NROW (RPB + 2)        // staged u rows (halo factor 1.25)

__device__ __forceinline__ float rfl(float x) {
    union { float f; int i; } c; c.f = x;
    c.i = __builtin_amdgcn_readfirstlane(c.i);   // wave-uniform -> SGPR
    return c.f;
}

__global__ __attribute__((amdgpu_flat_work_group_size(64, 64),
                          amdgpu_waves_per_eu(1, 2)))
void burgers_stencil(
    const float* __restrict__ u,
    const float* __restrict__ uvel,
    const float* __restrict__ w1,
    const float* __restrict__ w2,
    const float* __restrict__ w3,
    float* __restrict__ out,
    int rowBlocks, int colBlocks)
{
    const int lane = threadIdx.x;
    int rem = blockIdx.x;
    const int xb = rem % colBlocks; rem /= colBlocks;   // adjacent blocks share rows -> L2 halo hits
    const int yb = rem % rowBlocks; rem /= rowBlocks;
    const int b  = rem;

    const int y0 = yb * RPB;
    const int x0 = xb * CPW + lane * 4;

    const size_t img = (size_t)b * HH * WW;
    const float* ub  = u + img;

    // Weights -> SGPRs first (s_load, lgkmcnt, independent of the VMEM burst).
    float W1[9], W23[9];
#pragma unroll
    for (int i = 0; i < 9; ++i) {
        W1[i]  = rfl(w1[i]);
        W23[i] = rfl(w2[i] + w3[i]);    // fold: Lu = 0.5*c1 - vel*(c2+c3)
    }

    // Clamped halo columns: clamp IS the replicate pad, never OOB.
    const int xl = (x0 == 0) ? 0 : x0 - 1;
    const int xr = (x0 + 4 >= WW) ? WW - 1 : x0 + 4;

    // ---- the burst: 38 independent VMEM ops, ~18KB in flight per wave ----
    float4 uv[NROW]; float ul[NROW], ur[NROW];
#pragma unroll
    for (int i = 0; i < NROW; ++i) {
        int yr = y0 - 1 + i;
        yr = yr < 0 ? 0 : (yr > HH - 1 ? HH - 1 : yr);   // replicate pad rows
        const float* row = ub + (size_t)yr * WW;
        uv[i] = *(const float4*)(row + x0);
        ul[i] = row[xl];
        ur[i] = row[xr];
    }
    float4 vv[RPB];
#pragma unroll
    for (int r = 0; r < RPB; ++r)
        vv[r] = *(const float4*)(uvel + img + (size_t)(y0 + r) * WW + x0);

    __builtin_amdgcn_sched_barrier(0);  // burst stays above the math

    // ---- compute + store ----
#pragma unroll
    for (int r = 0; r < RPB; ++r) {
        float p[3][6];
#pragma unroll
        for (int rr = 0; rr < 3; ++rr) {
            const int i = r + rr;
            p[rr][0] = ul[i];
            p[rr][1] = uv[i].x; p[rr][2] = uv[i].y;
            p[rr][3] = uv[i].z; p[rr][4] = uv[i].w;
            p[rr][5] = ur[i];
        }
        const float vel[4] = {vv[r].x, vv[r].y, vv[r].z, vv[r].w};

        float o[4];
#pragma unroll
        for (int j = 0; j < 4; ++j) {
            float c1 = 0.f, c23 = 0.f;
#pragma unroll
            for (int rr = 0; rr < 3; ++rr) {
#pragma unroll
                for (int k = 0; k < 3; ++k) {
                    const float a = p[rr][j + k];
                    c1  = fmaf(W1[rr*3 + k],  a, c1);
                    c23 = fmaf(W23[rr*3 + k], a, c23);
                }
            }
            o[j] = fmaf(-vel[j], c23, 0.5f * c1);
        }
        float4 ov; ov.x = o[0]; ov.y = o[1]; ov.z = o[2]; ov.w = o[3];
        *(float4*)(out + img + (size_t)(y0 + r) * WW + x0) = ov;
    }
}

extern "C" void kernel_launch(void* const* d_in, const int* in_sizes, int n_in,
                              void* d_out, int out_size, void* d_ws, size_t ws_size,
                              hipStream_t stream) {
    const float* u    = (const float*)d_in[0];
    const float* uvel = (const float*)d_in[1];
    const float* w1   = (const float*)d_in[2];
    const float* w2   = (const float*)d_in[3];
    const float* w3   = (const float*)d_in[4];
    float* out        = (float*)d_out;

    const int B = in_sizes[0] / (HH * WW);      // 16
    const int rowBlocks = HH / RPB;             // 128
    const int colBlocks = WW / CPW;             // 4
    dim3 grid(B * rowBlocks * colBlocks);       // 8192 single-wave blocks
    dim3 block(64);
    burgers_stencil<<<grid, block, 0, stream>>>(u, uvel, w1, w2, w3, out,
                                                rowBlocks, colBlocks);
}